// Round 10
// baseline (207.339 us; speedup 1.0000x reference)
//
#include <hip/hip_runtime.h>

#define B_    16
#define CIN   32
#define H_    128
#define W_    128
#define COUT  32
#define OH_   256
#define OW_   256

typedef __attribute__((ext_vector_type(8))) short bf8_t;   // 8 bf16 (4 VGPRs)
typedef __attribute__((ext_vector_type(4))) float f32x4;

__device__ inline unsigned int f2bf(float f) {
    unsigned int u = __float_as_uint(f);
    return (u + 0x7fffu + ((u >> 16) & 1u)) >> 16;   // RNE
}

// ---- weights f32 [ci][co][kh][kw] -> bf16 wt[khkw][co][ci] (32 KB, L2-hot) ----
__global__ __launch_bounds__(256)
void prep_w(const float* __restrict__ wgt, unsigned short* __restrict__ wt) {
    int e = blockIdx.x * 256 + threadIdx.x;          // 16384 total
    int khkw = e >> 10, co = (e >> 5) & 31, ci = e & 31;
    wt[e] = (unsigned short)f2bf(wgt[(ci * COUT + co) * 16 + khkw]);
}

// ---- fused: read f32 x, transpose+cvt into LDS, MFMA, store f32 y ----
// Block: 4 t-rows (8 output rows) x 64 u-cols, all 32 co. 512 thr = 8 waves.
// Wave role (compute): ch = wv&1 (co half), trow = wv>>1 (0..3).
// MFMA operand order: A = x (M = 16 pixels), B = w (N = 16 co) -> D has
// row = pixel, col = co (m89 layout): lane holds co = ch*16 + (lane&15) and
// pixels m = (lane>>4)*4 + r, so (qo0,qo1) interleave -> 8 consecutive y
// floats per lane -> two nontemporal dwordx4 stores (halves store count,
// streams y past L2 so the x halo stays resident).
__global__ __launch_bounds__(512, 4)
void convt_fused(const float* __restrict__ x,
                 const unsigned short* __restrict__ wt,
                 const float* __restrict__ bias,
                 float* __restrict__ y) {
    __shared__ unsigned short xs[6 * 66 * 32];   // 25344 B

    const int tid  = threadIdx.x;
    const int lane = tid & 63;
    const int wv   = tid >> 6;
    const int n    = blockIdx.z;
    const int t0   = blockIdx.y * 4;
    const int u0   = blockIdx.x * 64;

    // ---- stage: combos (hr 0..5, g' 0..3); wave wv does c = wv, wv+8, wv+16.
#pragma unroll
    for (int j = 0; j < 3; ++j) {
        const int c  = wv + j * 8;
        const int hr = c >> 2, gp = c & 3;
        const int ih = t0 - 1 + hr;
        const int iw = u0 - 1 + lane;
        const bool inb = ((unsigned)ih < H_) && ((unsigned)iw < W_);
        const float* xq = x + (((long)(n * CIN + gp * 8) * H_ + ih) * W_ + iw);
        float v[8];
#pragma unroll
        for (int k = 0; k < 8; ++k)
            v[k] = inb ? xq[(long)k * (H_ * W_)] : 0.0f;
        uint4 pk;
        pk.x = f2bf(v[0]) | (f2bf(v[1]) << 16);
        pk.y = f2bf(v[2]) | (f2bf(v[3]) << 16);
        pk.z = f2bf(v[4]) | (f2bf(v[5]) << 16);
        pk.w = f2bf(v[6]) | (f2bf(v[7]) << 16);
        const int slot = gp ^ ((iw >> 1) & 3);
        *(uint4*)(xs + (hr * 66 + lane) * 32 + slot * 8) = pk;
    }
    // tail cells wc = 64, 65 (24 combos x 2): threads 0..47, one cell each
    if (tid < 48) {
        const int c  = tid >> 1;
        const int hr = c >> 2, gp = c & 3;
        const int wc = 64 + (tid & 1);
        const int ih = t0 - 1 + hr;
        const int iw = u0 - 1 + wc;
        const bool inb = ((unsigned)ih < H_) && ((unsigned)iw < W_);
        const float* xq = x + (((long)(n * CIN + gp * 8) * H_ + ih) * W_ + iw);
        float v[8];
#pragma unroll
        for (int k = 0; k < 8; ++k)
            v[k] = inb ? xq[(long)k * (H_ * W_)] : 0.0f;
        uint4 pk;
        pk.x = f2bf(v[0]) | (f2bf(v[1]) << 16);
        pk.y = f2bf(v[2]) | (f2bf(v[3]) << 16);
        pk.z = f2bf(v[4]) | (f2bf(v[5]) << 16);
        pk.w = f2bf(v[6]) | (f2bf(v[7]) << 16);
        const int slot = gp ^ ((iw >> 1) & 3);
        *(uint4*)(xs + (hr * 66 + wc) * 32 + slot * 8) = pk;
    }

    const int ch   = wv & 1;      // co half
    const int trow = wv >> 1;     // 0..3
    const int g    = lane >> 4;   // k-chunk (ci group)
    const int li   = lane & 15;   // input frags: x row (pixel) / w col (co)

    const float bv = bias[ch * 16 + li];   // D col = co = ch*16 + li

    __syncthreads();

    const int t = t0 + trow;
    const unsigned short* wp = wt + (ch * 16 + li) * 32 + g * 8;

#pragma unroll
    for (int po = 0; po < 2; ++po) {
        const int kh0 = po ? 0 : 1, dh0 = po ? 2 : 1;   // tap row A
        const int kh1 = po ? 2 : 3, dh1 = po ? 1 : 0;   // tap row B

        // 8 weight B-frags for this po (L1/L2-hot)
        bf8_t wfA[4], wfB[4];
#pragma unroll
        for (int kw = 0; kw < 4; ++kw) {
            wfA[kw] = *(const bf8_t*)(wp + (kh0 * 4 + kw) * 1024);
            wfB[kw] = *(const bf8_t*)(wp + (kh1 * 4 + kw) * 1024);
        }

#pragma unroll
        for (int st = 0; st < 4; ++st) {
            const int us = u0 + st * 16;

            bf8_t xfA[3], xfB[3];
#pragma unroll
            for (int dw = 0; dw < 3; ++dw) {
                const int wg   = us + li + dw - 1;
                const int wl   = wg - (u0 - 1);
                const int slot = g ^ ((wg >> 1) & 3);
                xfA[dw] = *(const bf8_t*)(xs + ((trow + dh0) * 66 + wl) * 32 + slot * 8);
                xfB[dw] = *(const bf8_t*)(xs + ((trow + dh1) * 66 + wl) * 32 + slot * 8);
            }

            f32x4 acc[2];
#pragma unroll
            for (int qo = 0; qo < 2; ++qo)
                acc[qo] = (f32x4){bv, bv, bv, bv};

#pragma unroll
            for (int qo = 0; qo < 2; ++qo) {
                const int dw0 = qo ? 2 : 1, kw0 = qo ? 0 : 1;
                const int dw1 = qo ? 1 : 0, kw1 = qo ? 2 : 3;
                acc[qo] = __builtin_amdgcn_mfma_f32_16x16x32_bf16(
                    xfA[dw0], wfA[kw0], acc[qo], 0, 0, 0);
                acc[qo] = __builtin_amdgcn_mfma_f32_16x16x32_bf16(
                    xfA[dw1], wfA[kw1], acc[qo], 0, 0, 0);
                acc[qo] = __builtin_amdgcn_mfma_f32_16x16x32_bf16(
                    xfB[dw0], wfB[kw0], acc[qo], 0, 0, 0);
                acc[qo] = __builtin_amdgcn_mfma_f32_16x16x32_bf16(
                    xfB[dw1], wfB[kw1], acc[qo], 0, 0, 0);
            }

            // store: lane -> co = ch*16+li, pixels m = g*4 + r (r=0..3).
            // (qo0,qo1) interleave -> 8 consecutive floats at ow = 2*(us+g*4).
            const int oh = 2 * t + po;
            const int co = ch * 16 + li;
            float* yp = y + (((long)(n * COUT + co) * OH_ + oh) * OW_)
                          + 2 * (us + g * 4);
            f32x4 s0 = {acc[0][0], acc[1][0], acc[0][1], acc[1][1]};
            f32x4 s1 = {acc[0][2], acc[1][2], acc[0][3], acc[1][3]};
            __builtin_nontemporal_store(s0, (f32x4*)yp);
            __builtin_nontemporal_store(s1, (f32x4*)(yp + 4));
        }
    }
}

extern "C" void kernel_launch(void* const* d_in, const int* in_sizes, int n_in,
                              void* d_out, int out_size, void* d_ws, size_t ws_size,
                              hipStream_t stream) {
    const float* x = (const float*)d_in[0];
    const float* w = (const float*)d_in[1];
    const float* b = (const float*)d_in[2];
    float* y = (float*)d_out;

    unsigned short* wt = (unsigned short*)d_ws;   // 32 KB

    prep_w<<<64, 256, 0, stream>>>(w, wt);
    convt_fused<<<dim3(W_ / 64, H_ / 4, B_), 512, 0, stream>>>(x, wt, b, y);
}

// Round 12
// 173.906 us; speedup vs baseline: 1.1922x; 1.1922x over previous
//
#include <hip/hip_runtime.h>

#define B_    16
#define CIN   32
#define H_    128
#define W_    128
#define COUT  32
#define OH_   256
#define OW_   256

typedef __attribute__((ext_vector_type(8))) short bf8_t;   // 8 bf16 (4 VGPRs)
typedef __attribute__((ext_vector_type(4))) float f32x4;

__device__ inline unsigned int f2bf(float f) {
    unsigned int u = __float_as_uint(f);
    return (u + 0x7fffu + ((u >> 16) & 1u)) >> 16;   // RNE
}

// ---- weights f32 [ci][co][kh][kw] -> bf16 wt[khkw][co][ci] (32 KB, L2-hot) ----
__global__ __launch_bounds__(256)
void prep_w(const float* __restrict__ wgt, unsigned short* __restrict__ wt) {
    int e = blockIdx.x * 256 + threadIdx.x;          // 16384 total
    int khkw = e >> 10, co = (e >> 5) & 31, ci = e & 31;
    wt[e] = (unsigned short)f2bf(wgt[(ci * COUT + co) * 16 + khkw]);
}

// issue 8 ci-plane loads for staging cell `cell` of combo c (hr = c>>2, gp = c&3)
__device__ __forceinline__ void issue8(const float* __restrict__ x, int n, int tt0,
                                       int u0, int c, int cell, float v[8]) {
    const int hr = c >> 2, gp = c & 3;
    const int ih = tt0 - 1 + hr;
    const int iw = u0 - 1 + cell;
    const bool inb = ((unsigned)ih < H_) && ((unsigned)iw < W_);
    const float* xq = x + (((long)(n * CIN + gp * 8) * H_ + ih) * W_ + iw);
#pragma unroll
    for (int k = 0; k < 8; ++k)
        v[k] = inb ? xq[(long)k * (H_ * W_)] : 0.0f;
}

// pack 8 f32 -> 8 bf16, ds_write_b128 into slot-swizzled LDS cell
__device__ __forceinline__ void pack_write(unsigned short* __restrict__ xsb, int u0,
                                           int c, int cell, const float v[8]) {
    const int hr = c >> 2, gp = c & 3;
    const int iw = u0 - 1 + cell;
    uint4 pk;
    pk.x = f2bf(v[0]) | (f2bf(v[1]) << 16);
    pk.y = f2bf(v[2]) | (f2bf(v[3]) << 16);
    pk.z = f2bf(v[4]) | (f2bf(v[5]) << 16);
    pk.w = f2bf(v[6]) | (f2bf(v[7]) << 16);
    const int slot = gp ^ ((iw >> 1) & 3);
    *(uint4*)(xsb + (hr * 66 + cell) * 32 + slot * 8) = pk;
}

// ---- fused: read f32 x, transpose+cvt into LDS, MFMA, store f32 y ----
// Block: 4 t-rows (8 output rows) x 64 u-cols, all 32 co. 512 thr = 8 waves.
// Stage phase issues ALL global loads (3x8 + tail 8) before any pack/ds_write
// so only one HBM latency is exposed instead of three serialized ones.
// MFMA operand order: A = x (M = 16 pixels), B = w (N = 16 co) -> lane owns
// 8 consecutive y floats -> two dwordx4 stores per (po,st), through L2
// (interleaved 16B chunks merge into full lines in L2; NT bypass was 1.55x
// write amplification in R10).
__global__ __launch_bounds__(512, 4)
void convt_fused(const float* __restrict__ x,
                 const unsigned short* __restrict__ wt,
                 const float* __restrict__ bias,
                 float* __restrict__ y) {
    __shared__ unsigned short xs[6 * 66 * 32];   // 25344 B

    const int tid  = threadIdx.x;
    const int lane = tid & 63;
    const int wv   = tid >> 6;
    const int n    = blockIdx.z;
    const int t0   = blockIdx.y * 4;
    const int u0   = blockIdx.x * 64;

    // ---- stage: issue everything, then pack everything
    float v[3][8];
#pragma unroll
    for (int j = 0; j < 3; ++j)
        issue8(x, n, t0, u0, wv + j * 8, lane, v[j]);
    const bool hasT = (tid < 48);
    float vT[8];
    if (hasT)
        issue8(x, n, t0, u0, tid >> 1, 64 + (tid & 1), vT);

#pragma unroll
    for (int j = 0; j < 3; ++j)
        pack_write(xs, u0, wv + j * 8, lane, v[j]);
    if (hasT)
        pack_write(xs, u0, tid >> 1, 64 + (tid & 1), vT);

    const int ch   = wv & 1;      // co half
    const int trow = wv >> 1;     // 0..3
    const int g    = lane >> 4;   // k-chunk (ci group)
    const int li   = lane & 15;   // input frags: x row (pixel) / w col (co)

    const float bv = bias[ch * 16 + li];   // D col = co = ch*16 + li

    __syncthreads();

    const int t = t0 + trow;
    const unsigned short* wp = wt + (ch * 16 + li) * 32 + g * 8;

#pragma unroll
    for (int po = 0; po < 2; ++po) {
        const int kh0 = po ? 0 : 1, dh0 = po ? 2 : 1;   // tap row A
        const int kh1 = po ? 2 : 3, dh1 = po ? 1 : 0;   // tap row B

        // 8 weight B-frags for this po (L1/L2-hot)
        bf8_t wfA[4], wfB[4];
#pragma unroll
        for (int kw = 0; kw < 4; ++kw) {
            wfA[kw] = *(const bf8_t*)(wp + (kh0 * 4 + kw) * 1024);
            wfB[kw] = *(const bf8_t*)(wp + (kh1 * 4 + kw) * 1024);
        }

#pragma unroll
        for (int st = 0; st < 4; ++st) {
            const int us = u0 + st * 16;

            bf8_t xfA[3], xfB[3];
#pragma unroll
            for (int dw = 0; dw < 3; ++dw) {
                const int wg   = us + li + dw - 1;
                const int wl   = wg - (u0 - 1);
                const int slot = g ^ ((wg >> 1) & 3);
                xfA[dw] = *(const bf8_t*)(xs + ((trow + dh0) * 66 + wl) * 32 + slot * 8);
                xfB[dw] = *(const bf8_t*)(xs + ((trow + dh1) * 66 + wl) * 32 + slot * 8);
            }

            f32x4 acc[2];
#pragma unroll
            for (int qo = 0; qo < 2; ++qo)
                acc[qo] = (f32x4){bv, bv, bv, bv};

#pragma unroll
            for (int qo = 0; qo < 2; ++qo) {
                const int dw0 = qo ? 2 : 1, kw0 = qo ? 0 : 1;
                const int dw1 = qo ? 1 : 0, kw1 = qo ? 2 : 3;
                acc[qo] = __builtin_amdgcn_mfma_f32_16x16x32_bf16(
                    xfA[dw0], wfA[kw0], acc[qo], 0, 0, 0);
                acc[qo] = __builtin_amdgcn_mfma_f32_16x16x32_bf16(
                    xfA[dw1], wfA[kw1], acc[qo], 0, 0, 0);
                acc[qo] = __builtin_amdgcn_mfma_f32_16x16x32_bf16(
                    xfB[dw0], wfB[kw0], acc[qo], 0, 0, 0);
                acc[qo] = __builtin_amdgcn_mfma_f32_16x16x32_bf16(
                    xfB[dw1], wfB[kw1], acc[qo], 0, 0, 0);
            }

            // store: lane -> co = ch*16+li, pixels m = g*4 + r (r=0..3).
            // (qo0,qo1) interleave -> 8 consecutive floats at ow = 2*(us+g*4).
            const int oh = 2 * t + po;
            const int co = ch * 16 + li;
            float* yp = y + (((long)(n * COUT + co) * OH_ + oh) * OW_)
                          + 2 * (us + g * 4);
            *(f32x4*)yp       = (f32x4){acc[0][0], acc[1][0], acc[0][1], acc[1][1]};
            *(f32x4*)(yp + 4) = (f32x4){acc[0][2], acc[1][2], acc[0][3], acc[1][3]};
        }
    }
}

extern "C" void kernel_launch(void* const* d_in, const int* in_sizes, int n_in,
                              void* d_out, int out_size, void* d_ws, size_t ws_size,
                              hipStream_t stream) {
    const float* x = (const float*)d_in[0];
    const float* w = (const float*)d_in[1];
    const float* b = (const float*)d_in[2];
    float* y = (float*)d_out;

    unsigned short* wt = (unsigned short*)d_ws;   // 32 KB

    prep_w<<<64, 256, 0, stream>>>(w, wt);
    convt_fused<<<dim3(W_ / 64, H_ / 4, B_), 512, 0, stream>>>(x, wt, b, y);
}